// Round 1
// baseline (12830.428 us; speedup 1.0000x reference)
//
#include <hip/hip_runtime.h>

// ---------------------------------------------------------------------------
// mLSTM (multiplicative LSTM) epitope/antigen model, MI355X fp16-MFMA version.
//
// Recurrence per step t:
//   hm = h @ wmh_n            (phase A GEMM, K=1920)
//   m  = (x @ wmx_n) ⊙ hm     (fused into phase A epilogue)
//   z  = m~ @ WhT~            (phase B GEMM, K=1952: x@wx and bias folded in
//                              via extra K-columns: m[.,1920..1929]=x_emb,
//                              m[.,1930]=1, WhT rows carry wx_n and b)
//   i,f,o,u = split(z); c = sig(f)c + sig(i)tanh(u); h = sig(o)tanh(c)
//   (gate-gathered tiles: each stepB WG owns 16 cols x 4 gates -> fused update)
//
// Both sequences run concatenated: rows 0..255 = total antigen (153 steps),
// rows 256..511 = epitope (first 25 steps only).
// ---------------------------------------------------------------------------

typedef _Float16 f16;
typedef _Float16 half8 __attribute__((ext_vector_type(8)));
typedef float f32x4 __attribute__((ext_vector_type(4)));

#define H_    1900
#define HP    1920   // padded hidden (30*64, 120*16)
#define KB    1952   // stepB K: 1920 + 10 (x-emb) + 1 (bias) + pad -> 61*32
#define NR    512    // total rows (256 tot + 256 epi)
#define NB_   256
#define TT    153
#define TE    25
#define EMB_  10
#define FCK   3840   // fc1 K (2*1900 padded)
#define FCN   384    // fc1 N (380 padded)

__device__ __forceinline__ void gl16(const void* g, void* l) {
  __builtin_amdgcn_global_load_lds(
      (const __attribute__((address_space(1))) void*)g,
      (__attribute__((address_space(3))) void*)l, 16, 0, 0);
}

__device__ __forceinline__ float sigm(float x) {
  float p = __expf(-fabsf(x));
  float r = 1.f / (1.f + p);
  return x >= 0.f ? r : 1.f - r;
}
__device__ __forceinline__ float tanh_(float x) {
  float p = __expf(-2.f * fabsf(x));
  float r = (1.f - p) / (1.f + p);
  return x >= 0.f ? r : -r;
}

// ---------------- prep kernels ----------------

// inverse L2 column norms * gain for all four weight-normed matrices
__global__ void k_norms(const float* __restrict__ wh, const float* __restrict__ wx,
                        const float* __restrict__ wmh, const float* __restrict__ wmx,
                        const float* __restrict__ gh, const float* __restrict__ gx,
                        const float* __restrict__ gmh, const float* __restrict__ gmx,
                        float* __restrict__ inv_wh, float* __restrict__ inv_wx,
                        float* __restrict__ inv_wmh, float* __restrict__ inv_wmx) {
  int tid = blockIdx.x * 256 + threadIdx.x;
  if (tid < 7600) {
    float s = 0.f;
    for (int k = 0; k < H_; k++) { float v = wh[(size_t)k * 7600 + tid]; s += v * v; }
    inv_wh[tid] = gh[tid] * rsqrtf(fmaxf(s, 1e-12f));
  } else if (tid < 15200) {
    int n = tid - 7600; float s = 0.f;
    for (int e = 0; e < EMB_; e++) { float v = wx[(size_t)e * 7600 + n]; s += v * v; }
    inv_wx[n] = gx[n] * rsqrtf(fmaxf(s, 1e-12f));
  } else if (tid < 17100) {
    int n = tid - 15200; float s = 0.f;
    for (int k = 0; k < H_; k++) { float v = wmh[(size_t)k * H_ + n]; s += v * v; }
    inv_wmh[n] = gmh[n] * rsqrtf(fmaxf(s, 1e-12f));
  } else if (tid < 19000) {
    int n = tid - 17100; float s = 0.f;
    for (int e = 0; e < EMB_; e++) { float v = wmx[(size_t)e * H_ + n]; s += v * v; }
    inv_wmx[n] = gmx[n] * rsqrtf(fmaxf(s, 1e-12f));
  }
}

// WmhT[n][k] = wmh[k][n]*inv_wmh[n], fp16, padded to [1920][1920]
__global__ void k_wmhT(const float* __restrict__ wmh, const float* __restrict__ inv,
                       f16* __restrict__ WmhT) {
  __shared__ float tl[32][33];
  int tx = threadIdx.x, ty = threadIdx.y;
  int kb = blockIdx.y * 32, nb = blockIdx.x * 32;
  #pragma unroll
  for (int i = 0; i < 4; i++) {
    int k = kb + ty + i * 8, n = nb + tx;
    tl[ty + i * 8][tx] = (k < H_ && n < H_) ? wmh[(size_t)k * H_ + n] * inv[n] : 0.f;
  }
  __syncthreads();
  #pragma unroll
  for (int i = 0; i < 4; i++) {
    int n = nb + ty + i * 8, k = kb + tx;
    WmhT[(size_t)n * HP + k] = (f16)tl[tx][ty + i * 8];
  }
}

// WhT[g][n][k]: k<1900 -> wh (normalized); k in [1920,1930) -> wx_n; k==1930 -> b
__global__ void k_whT(const float* __restrict__ wh, const float* __restrict__ wx,
                      const float* __restrict__ bias,
                      const float* __restrict__ inv_wh, const float* __restrict__ inv_wx,
                      f16* __restrict__ WhT) {
  __shared__ float tl[32][33];
  int tx = threadIdx.x, ty = threadIdx.y;
  int g = blockIdx.z;
  int kb = blockIdx.y * 32, nb = blockIdx.x * 32;
  #pragma unroll
  for (int i = 0; i < 4; i++) {
    int k = kb + ty + i * 8, n = nb + tx;
    float v = 0.f;
    if (n < H_) {
      int col = g * H_ + n;
      if (k < H_)                       v = wh[(size_t)k * 7600 + col] * inv_wh[col];
      else if (k >= HP && k < HP + EMB_) v = wx[(size_t)(k - HP) * 7600 + col] * inv_wx[col];
      else if (k == HP + EMB_)           v = bias[col];
    }
    tl[ty + i * 8][tx] = v;
  }
  __syncthreads();
  #pragma unroll
  for (int i = 0; i < 4; i++) {
    int n = nb + ty + i * 8, k = kb + tx;
    WhT[((size_t)g * HP + n) * KB + k] = (f16)tl[tx][ty + i * 8];
  }
}

__global__ void k_wmxn(const float* __restrict__ wmx, const float* __restrict__ inv_wmx,
                       float* __restrict__ wmxn) {
  int i = blockIdx.x * 256 + threadIdx.x;
  if (i >= EMB_ * HP) return;
  int e = i / HP, n = i % HP;
  wmxn[i] = (n < H_) ? wmx[(size_t)e * H_ + n] * inv_wmx[n] : 0.f;
}

__global__ void k_lens(const int* __restrict__ ex, const int* __restrict__ lx,
                       const int* __restrict__ rx, int* __restrict__ sel) {
  int s = threadIdx.x;
  int el = 0; for (int i = 0; i < 25; i++) el += (ex[s * 25 + i] != 26);
  int ll = 0; for (int i = 0; i < 64; i++) ll += (lx[s * 64 + i] != 26);
  int rl = 0; for (int i = 0; i < 64; i++) rl += (rx[s * 64 + i] != 26);
  ll = ll < 1 ? 1 : ll;  rl = rl < 1 ? 1 : rl;
  int tl = el + ll + rl;
  int ti = tl - 1; ti = ti < 0 ? 0 : (ti > 152 ? 152 : ti);
  int ei = el - 1; ei = ei < 0 ? 0 : (ei > 24 ? 24 : ei);
  sel[s] = ti; sel[256 + s] = ei;
}

// zero h0/h1/c; set m tail constants (bias column = 1, rest 0)
__global__ void k_init(f16* __restrict__ h0, f16* __restrict__ h1,
                       float* __restrict__ c, f16* __restrict__ m) {
  int i = blockIdx.x * 256 + threadIdx.x;
  if (i < NR * HP) { h0[i] = (f16)0.f; h1[i] = (f16)0.f; c[i] = 0.f; }
  if (i < NR * 32) {
    int r = i >> 5, cc = HP + (i & 31);
    m[(size_t)r * KB + cc] = (f16)((cc == HP + EMB_) ? 1.f : 0.f);
  }
}

// xe[t][row][e] = embed[token]
__global__ void k_embed(const int* __restrict__ totx, const int* __restrict__ epix,
                        const float* __restrict__ embed, float* __restrict__ xe) {
  int i = blockIdx.x * blockDim.x + threadIdx.x;
  if (i >= TT * NR) return;
  int t = i / NR, r = i % NR;
  int tok = -1;
  if (r < 256) tok = totx[r * TT + t];
  else if (t < TE) tok = epix[(r - 256) * TE + t];
  float* o = xe + (size_t)i * EMB_;
  if (tok >= 0) { for (int e = 0; e < EMB_; e++) o[e] = embed[tok * EMB_ + e]; }
  else          { for (int e = 0; e < EMB_; e++) o[e] = 0.f; }
}

// ---------------- recurrence kernels ----------------

// Phase A: hm = h @ WmhT  (tile [64 rows x 64 cols], K=1920), m = xm ⊙ hm
__global__ __launch_bounds__(64)
void k_stepA(const f16* __restrict__ h, const f16* __restrict__ WmhT,
             const float* __restrict__ xe_t, const float* __restrict__ wmxn,
             f16* __restrict__ m) {
  __shared__ __align__(16) f16 ha[2][64 * 32];
  __shared__ __align__(16) f16 wb[2][64 * 32];
  __shared__ float xmt[64 * 66];
  const int lane = threadIdx.x;
  const int r0 = blockIdx.y * 64, c0 = blockIdx.x * 64;

  auto stage = [&](int buf, int kb) {
    #pragma unroll
    for (int i = 0; i < 4; i++) {
      int ch = lane + 64 * i;
      gl16(h    + (size_t)(r0 + (ch >> 2)) * HP + kb + (ch & 3) * 8, &ha[buf][i * 512]);
      gl16(WmhT + (size_t)(c0 + (ch >> 2)) * HP + kb + (ch & 3) * 8, &wb[buf][i * 512]);
    }
  };
  stage(0, 0);

  { // xm tile (overlaps first staging latency). wmxn loads are wave-uniform.
    float xv[EMB_];
    #pragma unroll
    for (int e = 0; e < EMB_; e++) xv[e] = xe_t[(r0 + lane) * EMB_ + e];
    for (int n = 0; n < 64; n++) {
      float s = 0.f;
      #pragma unroll
      for (int e = 0; e < EMB_; e++) s += xv[e] * wmxn[e * HP + c0 + n];
      xmt[lane * 66 + n] = s;
    }
  }

  f32x4 acc[4][4];
  #pragma unroll
  for (int a = 0; a < 4; a++)
    #pragma unroll
    for (int b = 0; b < 4; b++) { f32x4 z = {0.f, 0.f, 0.f, 0.f}; acc[a][b] = z; }

  for (int kb = 0; kb < 60; ++kb) {
    int cur = kb & 1;
    if (kb + 1 < 60) { stage(cur ^ 1, (kb + 1) * 32); __builtin_amdgcn_s_waitcnt(0x0F78); }
    else             { __builtin_amdgcn_s_waitcnt(0x0F70); }
    half8 af[4], bf[4];
    #pragma unroll
    for (int rb = 0; rb < 4; rb++)
      af[rb] = *(const half8*)&ha[cur][(rb * 16 + (lane & 15)) * 32 + (lane >> 4) * 8];
    #pragma unroll
    for (int cb = 0; cb < 4; cb++)
      bf[cb] = *(const half8*)&wb[cur][(cb * 16 + (lane & 15)) * 32 + (lane >> 4) * 8];
    #pragma unroll
    for (int rb = 0; rb < 4; rb++)
      #pragma unroll
      for (int cb = 0; cb < 4; cb++)
        acc[rb][cb] = __builtin_amdgcn_mfma_f32_16x16x32_f16(af[rb], bf[cb], acc[rb][cb], 0, 0, 0);
  }

  const int q4 = lane >> 4, c16 = lane & 15;
  #pragma unroll
  for (int rb = 0; rb < 4; rb++)
    #pragma unroll
    for (int cb = 0; cb < 4; cb++)
      #pragma unroll
      for (int q = 0; q < 4; q++) {
        int rl = rb * 16 + q4 * 4 + q;
        int cl = cb * 16 + c16;
        float v = acc[rb][cb][q] * xmt[rl * 66 + cl];
        m[(size_t)(r0 + rl) * KB + c0 + cl] = (f16)v;
      }
  if (blockIdx.x == 0) {  // per-step K-extension columns: x embedding
    int row = r0 + lane;
    #pragma unroll
    for (int e = 0; e < EMB_; e++) m[(size_t)row * KB + HP + e] = (f16)xe_t[row * EMB_ + e];
  }
}

// Phase B: z = m~ @ WhT~ (tile [64 rows x (16 cols x 4 gates)], K=1952) + gate update
__global__ __launch_bounds__(64)
void k_stepB(const f16* __restrict__ m, const f16* __restrict__ WhT,
             float* __restrict__ c, f16* __restrict__ hout,
             float* __restrict__ selH, const int* __restrict__ sel, int t) {
  __shared__ __align__(16) f16 ma[2][64 * 32];
  __shared__ __align__(16) f16 wb[2][64 * 32];
  const int lane = threadIdx.x;
  const int r0 = blockIdx.y * 64, c0 = blockIdx.x * 16;

  auto stage = [&](int buf, int kb) {
    #pragma unroll
    for (int i = 0; i < 4; i++) {
      int ch = lane + 64 * i;
      gl16(m + (size_t)(r0 + (ch >> 2)) * KB + kb + (ch & 3) * 8, &ma[buf][i * 512]);
      int nr = ch >> 2;
      gl16(WhT + ((size_t)(nr >> 4) * HP + c0 + (nr & 15)) * KB + kb + (ch & 3) * 8,
           &wb[buf][i * 512]);
    }
  };
  stage(0, 0);

  f32x4 acc[4][4];  // [row-block][gate]
  #pragma unroll
  for (int a = 0; a < 4; a++)
    #pragma unroll
    for (int b = 0; b < 4; b++) { f32x4 z = {0.f, 0.f, 0.f, 0.f}; acc[a][b] = z; }

  for (int kb = 0; kb < 61; ++kb) {
    int cur = kb & 1;
    if (kb + 1 < 61) { stage(cur ^ 1, (kb + 1) * 32); __builtin_amdgcn_s_waitcnt(0x0F78); }
    else             { __builtin_amdgcn_s_waitcnt(0x0F70); }
    half8 af[4], bf[4];
    #pragma unroll
    for (int rb = 0; rb < 4; rb++)
      af[rb] = *(const half8*)&ma[cur][(rb * 16 + (lane & 15)) * 32 + (lane >> 4) * 8];
    #pragma unroll
    for (int g = 0; g < 4; g++)
      bf[g] = *(const half8*)&wb[cur][(g * 16 + (lane & 15)) * 32 + (lane >> 4) * 8];
    #pragma unroll
    for (int rb = 0; rb < 4; rb++)
      #pragma unroll
      for (int g = 0; g < 4; g++)
        acc[rb][g] = __builtin_amdgcn_mfma_f32_16x16x32_f16(af[rb], bf[g], acc[rb][g], 0, 0, 0);
  }

  const int q4 = lane >> 4, c16 = lane & 15;
  const int j = c0 + c16;
  const bool valid = j < H_;
  #pragma unroll
  for (int rb = 0; rb < 4; rb++)
    #pragma unroll
    for (int q = 0; q < 4; q++) {
      int row = r0 + rb * 16 + q4 * 4 + q;
      size_t idx = (size_t)row * HP + j;
      if (valid) {
        float cold = c[idx];
        float iz = acc[rb][0][q], fz = acc[rb][1][q];
        float oz = acc[rb][2][q], uz = acc[rb][3][q];
        float cn = sigm(fz) * cold + sigm(iz) * tanh_(uz);
        float hv = sigm(oz) * tanh_(cn);
        c[idx] = cn;
        hout[idx] = (f16)hv;
        if (t == sel[row]) selH[idx] = hv;
      } else {
        c[idx] = 0.f; hout[idx] = (f16)0.f;
      }
    }
}

// ---------------- classifier ----------------

__global__ void k_xq(const float* __restrict__ selH, const float* __restrict__ g1,
                     const float* __restrict__ be1, const float* __restrict__ mu1,
                     const float* __restrict__ var1, f16* __restrict__ xq) {
  int i = blockIdx.x * 256 + threadIdx.x;
  if (i >= 256 * FCK) return;
  int s = i / FCK, k = i % FCK;
  float v = 0.f;
  if (k < H_)            v = selH[(size_t)s * HP + k];
  else if (k < 2 * H_)   v = selH[(size_t)(256 + s) * HP + (k - H_)];
  float lr = v < 0.f ? 0.3f * v : v;
  float q = 0.f;
  if (k < 2 * H_) q = (lr - mu1[k]) * rsqrtf(var1[k] + 1e-3f) * g1[k] + be1[k];
  xq[i] = (f16)q;
}

__global__ void k_w1t(const float* __restrict__ W1, f16* __restrict__ W1T) {
  int i = blockIdx.x * 256 + threadIdx.x;
  if (i >= FCN * FCK) return;
  int cidx = i / FCK, k = i % FCK;
  W1T[i] = (f16)((cidx < 380 && k < 2 * H_) ? W1[(size_t)k * 380 + cidx] : 0.f);
}

__global__ __launch_bounds__(64)
void k_fc1(const f16* __restrict__ xq, const f16* __restrict__ W1T,
           const float* __restrict__ b1, float* __restrict__ z1) {
  __shared__ __align__(16) f16 ha[2][64 * 32];
  __shared__ __align__(16) f16 wb[2][64 * 32];
  const int lane = threadIdx.x;
  const int r0 = blockIdx.y * 64, c0 = blockIdx.x * 64;
  auto stage = [&](int buf, int kb) {
    #pragma unroll
    for (int i = 0; i < 4; i++) {
      int ch = lane + 64 * i;
      gl16(xq  + (size_t)(r0 + (ch >> 2)) * FCK + kb + (ch & 3) * 8, &ha[buf][i * 512]);
      gl16(W1T + (size_t)(c0 + (ch >> 2)) * FCK + kb + (ch & 3) * 8, &wb[buf][i * 512]);
    }
  };
  stage(0, 0);
  f32x4 acc[4][4];
  #pragma unroll
  for (int a = 0; a < 4; a++)
    #pragma unroll
    for (int b = 0; b < 4; b++) { f32x4 z = {0.f, 0.f, 0.f, 0.f}; acc[a][b] = z; }
  for (int kb = 0; kb < 120; ++kb) {
    int cur = kb & 1;
    if (kb + 1 < 120) { stage(cur ^ 1, (kb + 1) * 32); __builtin_amdgcn_s_waitcnt(0x0F78); }
    else              { __builtin_amdgcn_s_waitcnt(0x0F70); }
    half8 af[4], bf[4];
    #pragma unroll
    for (int rb = 0; rb < 4; rb++)
      af[rb] = *(const half8*)&ha[cur][(rb * 16 + (lane & 15)) * 32 + (lane >> 4) * 8];
    #pragma unroll
    for (int cb = 0; cb < 4; cb++)
      bf[cb] = *(const half8*)&wb[cur][(cb * 16 + (lane & 15)) * 32 + (lane >> 4) * 8];
    #pragma unroll
    for (int rb = 0; rb < 4; rb++)
      #pragma unroll
      for (int cb = 0; cb < 4; cb++)
        acc[rb][cb] = __builtin_amdgcn_mfma_f32_16x16x32_f16(af[rb], bf[cb], acc[rb][cb], 0, 0, 0);
  }
  const int q4 = lane >> 4, c16 = lane & 15;
  #pragma unroll
  for (int rb = 0; rb < 4; rb++)
    #pragma unroll
    for (int cb = 0; cb < 4; cb++)
      #pragma unroll
      for (int q = 0; q < 4; q++) {
        int rl = rb * 16 + q4 * 4 + q;
        int cl = cb * 16 + c16;
        int col = c0 + cl;
        float bias = (col < 380) ? b1[col] : 0.f;
        z1[(size_t)(r0 + rl) * FCN + col] = acc[rb][cb][q] + bias;
      }
}

__global__ void k_fc2(const float* __restrict__ z1, const float* __restrict__ g2,
                      const float* __restrict__ be2, const float* __restrict__ mu2,
                      const float* __restrict__ var2, const float* __restrict__ W2,
                      const float* __restrict__ b2, float* __restrict__ out) {
  int s = threadIdx.x;
  float a = 0.f;
  for (int jj = 0; jj < 380; jj++) {
    float v = z1[(size_t)s * FCN + jj];
    float lr = v < 0.f ? 0.3f * v : v;
    float q = (lr - mu2[jj]) * rsqrtf(var2[jj] + 1e-3f) * g2[jj] + be2[jj];
    a += q * W2[jj];
  }
  out[s] = a + b2[0];
}

// ---------------- host ----------------

extern "C" void kernel_launch(void* const* d_in, const int* in_sizes, int n_in,
                              void* d_out, int out_size, void* d_ws, size_t ws_size,
                              hipStream_t stream) {
  const int*   epix  = (const int*)d_in[0];
  const int*   lx    = (const int*)d_in[1];
  const int*   rx    = (const int*)d_in[2];
  const int*   totx  = (const int*)d_in[3];
  const float* embed = (const float*)d_in[4];
  const float* wx    = (const float*)d_in[5];
  const float* wh    = (const float*)d_in[6];
  const float* wmx   = (const float*)d_in[7];
  const float* wmh   = (const float*)d_in[8];
  const float* bb    = (const float*)d_in[9];
  const float* gx    = (const float*)d_in[10];
  const float* gh    = (const float*)d_in[11];
  const float* gmx   = (const float*)d_in[12];
  const float* gmh   = (const float*)d_in[13];
  const float* bn1g  = (const float*)d_in[14];
  const float* bn1b  = (const float*)d_in[15];
  const float* bn1m  = (const float*)d_in[16];
  const float* bn1v  = (const float*)d_in[17];
  const float* W1    = (const float*)d_in[18];
  const float* b1    = (const float*)d_in[19];
  const float* bn2g  = (const float*)d_in[20];
  const float* bn2b  = (const float*)d_in[21];
  const float* bn2m  = (const float*)d_in[22];
  const float* bn2v  = (const float*)d_in[23];
  const float* W2    = (const float*)d_in[24];
  const float* b2v   = (const float*)d_in[25];

  char* base = (char*)d_ws;
  size_t off = 0;
  auto alloc = [&](size_t n) { char* p = base + off; off = (off + n + 255) & ~(size_t)255; return p; };

  f16*   WmhT   = (f16*)  alloc((size_t)HP * HP * 2);
  f16*   WhT    = (f16*)  alloc((size_t)4 * HP * KB * 2);
  float* wmxn   = (float*)alloc((size_t)EMB_ * HP * 4);
  float* xe     = (float*)alloc((size_t)TT * NR * EMB_ * 4);
  f16*   h0     = (f16*)  alloc((size_t)NR * HP * 2);
  f16*   h1     = (f16*)  alloc((size_t)NR * HP * 2);
  f16*   mbuf   = (f16*)  alloc((size_t)NR * KB * 2);
  float* cst    = (float*)alloc((size_t)NR * HP * 4);
  float* selH   = (float*)alloc((size_t)NR * HP * 4);
  int*   sel    = (int*)  alloc((size_t)NR * 4);
  float* inv_wh = (float*)alloc(7600 * 4);
  float* inv_wx = (float*)alloc(7600 * 4);
  float* inv_wmh= (float*)alloc(1900 * 4);
  float* inv_wmx= (float*)alloc(1900 * 4);
  f16*   xq     = (f16*)  alloc((size_t)256 * FCK * 2);
  f16*   W1T    = (f16*)  alloc((size_t)FCN * FCK * 2);
  float* z1     = (float*)alloc((size_t)256 * FCN * 4);
  (void)in_sizes; (void)n_in; (void)out_size; (void)ws_size;

  hipLaunchKernelGGL(k_norms, dim3(75), dim3(256), 0, stream,
                     wh, wx, wmh, wmx, gh, gx, gmh, gmx, inv_wh, inv_wx, inv_wmh, inv_wmx);
  hipLaunchKernelGGL(k_wmhT, dim3(60, 60), dim3(32, 8), 0, stream, wmh, inv_wmh, WmhT);
  hipLaunchKernelGGL(k_whT, dim3(60, 61, 4), dim3(32, 8), 0, stream,
                     wh, wx, bb, inv_wh, inv_wx, WhT);
  hipLaunchKernelGGL(k_wmxn, dim3((EMB_ * HP + 255) / 256), dim3(256), 0, stream,
                     wmx, inv_wmx, wmxn);
  hipLaunchKernelGGL(k_lens, dim3(1), dim3(256), 0, stream, epix, lx, rx, sel);
  hipLaunchKernelGGL(k_init, dim3((NR * HP + 255) / 256), dim3(256), 0, stream,
                     h0, h1, cst, mbuf);
  hipLaunchKernelGGL(k_embed, dim3((TT * NR + 255) / 256), dim3(256), 0, stream,
                     totx, epix, embed, xe);

  for (int t = 0; t < TT; t++) {
    int Mt = (t < TE) ? NR : NB_;
    const f16* hin = (t & 1) ? h1 : h0;
    f16*       ho  = (t & 1) ? h0 : h1;
    hipLaunchKernelGGL(k_stepA, dim3(30, Mt / 64), dim3(64), 0, stream,
                       hin, WmhT, xe + (size_t)t * NR * EMB_, wmxn, mbuf);
    hipLaunchKernelGGL(k_stepB, dim3(119, Mt / 64), dim3(64), 0, stream,
                       mbuf, WhT, cst, ho, selH, sel, t);
  }

  hipLaunchKernelGGL(k_xq, dim3((256 * FCK + 255) / 256), dim3(256), 0, stream,
                     selH, bn1g, bn1b, bn1m, bn1v, xq);
  hipLaunchKernelGGL(k_w1t, dim3((FCN * FCK + 255) / 256), dim3(256), 0, stream, W1, W1T);
  hipLaunchKernelGGL(k_fc1, dim3(6, 4), dim3(64), 0, stream, xq, W1T, b1, z1);
  hipLaunchKernelGGL(k_fc2, dim3(1), dim3(256), 0, stream,
                     z1, bn2g, bn2b, bn2m, bn2v, W2, b2v, (float*)d_out);
}

// Round 2
// 8490.239 us; speedup vs baseline: 1.5112x; 1.5112x over previous
//
#include <hip/hip_runtime.h>

// ---------------------------------------------------------------------------
// mLSTM epitope/antigen model, MI355X fp16-MFMA version, round 2.
//
// R2 changes vs R1 (12.83 ms):
//  - 4-deep gl16->LDS pipeline (was 2) with peeled vmcnt tails: covers
//    ~750cy of load latency per wave instead of ~170cy.
//  - stepA retiled 16 rows x 64 cols -> 480/960 single-wave blocks (was
//    120/240); xm computed via an extra MFMA (xe16 @ wmxT) whose C-layout
//    matches hm's -> register elementwise product, no LDS xm tile.
//  - XCD swizzle: row-blocks sharing a weight col-block land on the same
//    XCD (id%8 round-robin) so B-tile re-reads hit that XCD's L2.
// ---------------------------------------------------------------------------

typedef _Float16 f16;
typedef _Float16 half8 __attribute__((ext_vector_type(8)));
typedef float f32x4 __attribute__((ext_vector_type(4)));

#define H_    1900
#define HP    1920   // padded hidden
#define KB    1952   // stepB K: 1920 + 10 (x-emb) + 1 (bias) + pad (61*32)
#define NR    512
#define NB_   256
#define TT    153
#define TE    25
#define EMB_  10
#define FCK   3840
#define FCN   384

// s_waitcnt imm: vmcnt low4 | exp<<4 | lgkm<<8 | vmcnt-high<<14
#define WAITVM(N) __builtin_amdgcn_s_waitcnt(((N)&0xF) | (0x7<<4) | (0xF<<8) | (((N)>>4)<<14))

__device__ __forceinline__ void gl16(const void* g, void* l) {
  __builtin_amdgcn_global_load_lds(
      (const __attribute__((address_space(1))) void*)g,
      (__attribute__((address_space(3))) void*)l, 16, 0, 0);
}

__device__ __forceinline__ float sigm(float x) {
  float p = __expf(-fabsf(x));
  float r = 1.f / (1.f + p);
  return x >= 0.f ? r : 1.f - r;
}
__device__ __forceinline__ float tanh_(float x) {
  float p = __expf(-2.f * fabsf(x));
  float r = (1.f - p) / (1.f + p);
  return x >= 0.f ? r : -r;
}

// ---------------- prep kernels ----------------

__global__ void k_norms(const float* __restrict__ wh, const float* __restrict__ wx,
                        const float* __restrict__ wmh, const float* __restrict__ wmx,
                        const float* __restrict__ gh, const float* __restrict__ gx,
                        const float* __restrict__ gmh, const float* __restrict__ gmx,
                        float* __restrict__ inv_wh, float* __restrict__ inv_wx,
                        float* __restrict__ inv_wmh, float* __restrict__ inv_wmx) {
  int tid = blockIdx.x * 256 + threadIdx.x;
  if (tid < 7600) {
    float s = 0.f;
    for (int k = 0; k < H_; k++) { float v = wh[(size_t)k * 7600 + tid]; s += v * v; }
    inv_wh[tid] = gh[tid] * rsqrtf(fmaxf(s, 1e-12f));
  } else if (tid < 15200) {
    int n = tid - 7600; float s = 0.f;
    for (int e = 0; e < EMB_; e++) { float v = wx[(size_t)e * 7600 + n]; s += v * v; }
    inv_wx[n] = gx[n] * rsqrtf(fmaxf(s, 1e-12f));
  } else if (tid < 17100) {
    int n = tid - 15200; float s = 0.f;
    for (int k = 0; k < H_; k++) { float v = wmh[(size_t)k * H_ + n]; s += v * v; }
    inv_wmh[n] = gmh[n] * rsqrtf(fmaxf(s, 1e-12f));
  } else if (tid < 19000) {
    int n = tid - 17100; float s = 0.f;
    for (int e = 0; e < EMB_; e++) { float v = wmx[(size_t)e * H_ + n]; s += v * v; }
    inv_wmx[n] = gmx[n] * rsqrtf(fmaxf(s, 1e-12f));
  }
}

// WmhT[n][k] = wmh[k][n]*inv[n], fp16, [1920][1920]
__global__ void k_wmhT(const float* __restrict__ wmh, const float* __restrict__ inv,
                       f16* __restrict__ WmhT) {
  __shared__ float tl[32][33];
  int tx = threadIdx.x, ty = threadIdx.y;
  int kb = blockIdx.y * 32, nb = blockIdx.x * 32;
  #pragma unroll
  for (int i = 0; i < 4; i++) {
    int k = kb + ty + i * 8, n = nb + tx;
    tl[ty + i * 8][tx] = (k < H_ && n < H_) ? wmh[(size_t)k * H_ + n] * inv[n] : 0.f;
  }
  __syncthreads();
  #pragma unroll
  for (int i = 0; i < 4; i++) {
    int n = nb + ty + i * 8, k = kb + tx;
    WmhT[(size_t)n * HP + k] = (f16)tl[tx][ty + i * 8];
  }
}

// WhT[g][n][k]: k<1900 -> wh_n; k in [1920,1930) -> wx_n; k==1930 -> b
__global__ void k_whT(const float* __restrict__ wh, const float* __restrict__ wx,
                      const float* __restrict__ bias,
                      const float* __restrict__ inv_wh, const float* __restrict__ inv_wx,
                      f16* __restrict__ WhT) {
  __shared__ float tl[32][33];
  int tx = threadIdx.x, ty = threadIdx.y;
  int g = blockIdx.z;
  int kb = blockIdx.y * 32, nb = blockIdx.x * 32;
  #pragma unroll
  for (int i = 0; i < 4; i++) {
    int k = kb + ty + i * 8, n = nb + tx;
    float v = 0.f;
    if (n < H_) {
      int col = g * H_ + n;
      if (k < H_)                        v = wh[(size_t)k * 7600 + col] * inv_wh[col];
      else if (k >= HP && k < HP + EMB_) v = wx[(size_t)(k - HP) * 7600 + col] * inv_wx[col];
      else if (k == HP + EMB_)           v = bias[col];
    }
    tl[ty + i * 8][tx] = v;
  }
  __syncthreads();
  #pragma unroll
  for (int i = 0; i < 4; i++) {
    int n = nb + ty + i * 8, k = kb + tx;
    WhT[((size_t)g * HP + n) * KB + k] = (f16)tl[tx][ty + i * 8];
  }
}

// wmxT[n][32]: k<10 -> wmx_n[k][n], else 0  (B operand of the xm-MFMA)
__global__ void k_wmxT(const float* __restrict__ wmx, const float* __restrict__ inv_wmx,
                       f16* __restrict__ wmxT) {
  int i = blockIdx.x * 256 + threadIdx.x;
  if (i >= HP * 32) return;
  int n = i >> 5, k = i & 31;
  float v = (k < EMB_ && n < H_) ? wmx[(size_t)k * H_ + n] * inv_wmx[n] : 0.f;
  wmxT[i] = (f16)v;
}

__global__ void k_lens(const int* __restrict__ ex, const int* __restrict__ lx,
                       const int* __restrict__ rx, int* __restrict__ sel) {
  int s = threadIdx.x;
  int el = 0; for (int i = 0; i < 25; i++) el += (ex[s * 25 + i] != 26);
  int ll = 0; for (int i = 0; i < 64; i++) ll += (lx[s * 64 + i] != 26);
  int rl = 0; for (int i = 0; i < 64; i++) rl += (rx[s * 64 + i] != 26);
  ll = ll < 1 ? 1 : ll;  rl = rl < 1 ? 1 : rl;
  int tl = el + ll + rl;
  int ti = tl - 1; ti = ti < 0 ? 0 : (ti > 152 ? 152 : ti);
  int ei = el - 1; ei = ei < 0 ? 0 : (ei > 24 ? 24 : ei);
  sel[s] = ti; sel[256 + s] = ei;
}

__global__ void k_init(f16* __restrict__ h0, f16* __restrict__ h1, float* __restrict__ c) {
  int i = blockIdx.x * 256 + threadIdx.x;
  if (i < NR * HP) { h0[i] = (f16)0.f; h1[i] = (f16)0.f; c[i] = 0.f; }
}

// xe16[t][row][32]: cols 0..9 = embed[token], col 10 = 1.0 (bias), rest 0
__global__ void k_xe16(const int* __restrict__ totx, const int* __restrict__ epix,
                       const float* __restrict__ embed, f16* __restrict__ xe16) {
  int i = blockIdx.x * blockDim.x + threadIdx.x;
  if (i >= TT * NR) return;
  int t = i / NR, r = i % NR;
  int tok = -1;
  if (r < 256) tok = totx[r * TT + t];
  else if (t < TE) tok = epix[(r - 256) * TE + t];
  f16* o = xe16 + (size_t)i * 32;
  #pragma unroll
  for (int e = 0; e < EMB_; e++) o[e] = (f16)(tok >= 0 ? embed[tok * EMB_ + e] : 0.f);
  o[10] = (f16)1.f;
  #pragma unroll
  for (int e = 11; e < 32; e++) o[e] = (f16)0.f;
}

// ---------------- recurrence kernels ----------------

// Phase A: tile 16 rows x 64 cols, K=1920 (60 iters), DEPTH=4, 5 loads/iter.
// m = (xe16 @ wmxT) * (h @ WmhT)  -- xm via one MFMA set, same C-layout.
__global__ __launch_bounds__(64)
void k_stepA(const f16* __restrict__ h, const f16* __restrict__ WmhT,
             const f16* __restrict__ xe16_t, const f16* __restrict__ wmxT,
             f16* __restrict__ m, int lnper) {
  __shared__ __align__(16) f16 ha[4][16 * 32];
  __shared__ __align__(16) f16 wb[4][64 * 32];
  const int lane = threadIdx.x;
  int id = blockIdx.x;
  int g = id >> lnper, rem = id & ((1 << lnper) - 1);
  int r = rem >> 3, x = rem & 7;
  int cblk = g * 8 + x;
  if (cblk >= 30) return;
  const int r0 = r * 16, c0 = cblk * 64;

  auto stage = [&](int buf, int kb) {
    // A: 16 rows x 32 k = 1KB = 1 issue
    gl16(h + (size_t)(r0 + (lane >> 2)) * HP + kb + (lane & 3) * 8, &ha[buf][0]);
    // B: 64 n x 32 k = 4KB = 4 issues
    #pragma unroll
    for (int i = 0; i < 4; i++) {
      int ch = lane + 64 * i;
      gl16(WmhT + (size_t)(c0 + (ch >> 2)) * HP + kb + (ch & 3) * 8, &wb[buf][i * 512]);
    }
  };

  // xm fragments (direct global->reg, compiler-managed waits)
  half8 xa = *(const half8*)(xe16_t + (size_t)(r0 + (lane & 15)) * 32 + (lane >> 4) * 8);
  half8 xbf[4];
  #pragma unroll
  for (int cb = 0; cb < 4; cb++)
    xbf[cb] = *(const half8*)(wmxT + (size_t)(c0 + cb * 16 + (lane & 15)) * 32 + (lane >> 4) * 8);

  stage(0, 0); stage(1, 32); stage(2, 64);

  f32x4 xm[4];
  #pragma unroll
  for (int cb = 0; cb < 4; cb++) {
    f32x4 z = {0.f, 0.f, 0.f, 0.f};
    xm[cb] = __builtin_amdgcn_mfma_f32_16x16x32_f16(xa, xbf[cb], z, 0, 0, 0);
  }

  f32x4 acc[4];
  #pragma unroll
  for (int cb = 0; cb < 4; cb++) { f32x4 z = {0.f, 0.f, 0.f, 0.f}; acc[cb] = z; }

  auto compute = [&](int buf) {
    half8 af = *(const half8*)&ha[buf][(lane & 15) * 32 + (lane >> 4) * 8];
    #pragma unroll
    for (int cb = 0; cb < 4; cb++) {
      half8 bf = *(const half8*)&wb[buf][(cb * 16 + (lane & 15)) * 32 + (lane >> 4) * 8];
      acc[cb] = __builtin_amdgcn_mfma_f32_16x16x32_f16(af, bf, acc[cb], 0, 0, 0);
    }
  };

  for (int kb = 0; kb <= 56; ++kb) {            // kb+3 <= 59
    stage((kb + 3) & 3, (kb + 3) * 32);
    WAITVM(15);
    compute(kb & 3);
  }
  WAITVM(10); compute(57 & 3);
  WAITVM(5);  compute(58 & 3);
  WAITVM(0);  compute(59 & 3);

  const int q4 = lane >> 4, c16 = lane & 15;
  #pragma unroll
  for (int cb = 0; cb < 4; cb++)
    #pragma unroll
    for (int q = 0; q < 4; q++) {
      int row = q4 * 4 + q, col = cb * 16 + c16;
      m[(size_t)(r0 + row) * KB + c0 + col] = (f16)(acc[cb][q] * xm[cb][q]);
    }
  if (cblk == 0) {  // K-extension tail (cols 1920..1951) = xe16 row (bias col incl.)
    int row = lane >> 2, koff = (lane & 3) * 8;
    half8 v = *(const half8*)(xe16_t + (size_t)(r0 + row) * 32 + koff);
    *(half8*)(m + (size_t)(r0 + row) * KB + HP + koff) = v;
  }
}

// Phase B: tile 64 rows x (16 cols x 4 gates), K=1952 (61 iters), DEPTH=4,
// 8 loads/iter, fused gate epilogue.
__global__ __launch_bounds__(64)
void k_stepB(const f16* __restrict__ m, const f16* __restrict__ WhT,
             float* __restrict__ c, f16* __restrict__ hout,
             float* __restrict__ selH, const int* __restrict__ sel, int t, int lnper) {
  __shared__ __align__(16) f16 ma[4][64 * 32];
  __shared__ __align__(16) f16 wb[4][64 * 32];
  const int lane = threadIdx.x;
  int id = blockIdx.x;
  int g = id >> lnper, rem = id & ((1 << lnper) - 1);
  int r = rem >> 3, x = rem & 7;
  int cblk = g * 8 + x;
  if (cblk >= 119) return;
  const int r0 = r * 64, c0 = cblk * 16;

  auto stage = [&](int buf, int kb) {
    #pragma unroll
    for (int i = 0; i < 4; i++) {
      int ch = lane + 64 * i;
      gl16(m + (size_t)(r0 + (ch >> 2)) * KB + kb + (ch & 3) * 8, &ma[buf][i * 512]);
      int nr = ch >> 2;
      gl16(WhT + ((size_t)(nr >> 4) * HP + c0 + (nr & 15)) * KB + kb + (ch & 3) * 8,
           &wb[buf][i * 512]);
    }
  };
  stage(0, 0); stage(1, 32); stage(2, 64);

  f32x4 acc[4][4];  // [row-block][gate]
  #pragma unroll
  for (int a = 0; a < 4; a++)
    #pragma unroll
    for (int b = 0; b < 4; b++) { f32x4 z = {0.f, 0.f, 0.f, 0.f}; acc[a][b] = z; }

  auto compute = [&](int buf) {
    half8 af[4], bf[4];
    #pragma unroll
    for (int rb = 0; rb < 4; rb++)
      af[rb] = *(const half8*)&ma[buf][(rb * 16 + (lane & 15)) * 32 + (lane >> 4) * 8];
    #pragma unroll
    for (int gg = 0; gg < 4; gg++)
      bf[gg] = *(const half8*)&wb[buf][(gg * 16 + (lane & 15)) * 32 + (lane >> 4) * 8];
    #pragma unroll
    for (int rb = 0; rb < 4; rb++)
      #pragma unroll
      for (int gg = 0; gg < 4; gg++)
        acc[rb][gg] = __builtin_amdgcn_mfma_f32_16x16x32_f16(af[rb], bf[gg], acc[rb][gg], 0, 0, 0);
  };

  for (int kb = 0; kb <= 57; ++kb) {            // kb+3 <= 60
    stage((kb + 3) & 3, (kb + 3) * 32);
    WAITVM(24);
    compute(kb & 3);
  }
  WAITVM(16); compute(58 & 3);
  WAITVM(8);  compute(59 & 3);
  WAITVM(0);  compute(60 & 3);

  const int q4 = lane >> 4, c16 = lane & 15;
  const int j = c0 + c16;
  const bool valid = j < H_;
  #pragma unroll
  for (int rb = 0; rb < 4; rb++)
    #pragma unroll
    for (int q = 0; q < 4; q++) {
      int row = r0 + rb * 16 + q4 * 4 + q;
      size_t idx = (size_t)row * HP + j;
      if (valid) {
        float cold = c[idx];
        float iz = acc[rb][0][q], fz = acc[rb][1][q];
        float oz = acc[rb][2][q], uz = acc[rb][3][q];
        float cn = sigm(fz) * cold + sigm(iz) * tanh_(uz);
        float hv = sigm(oz) * tanh_(cn);
        c[idx] = cn;
        hout[idx] = (f16)hv;
        if (t == sel[row]) selH[idx] = hv;
      } else {
        c[idx] = 0.f; hout[idx] = (f16)0.f;
      }
    }
}

// ---------------- classifier ----------------

__global__ void k_xq(const float* __restrict__ selH, const float* __restrict__ g1,
                     const float* __restrict__ be1, const float* __restrict__ mu1,
                     const float* __restrict__ var1, f16* __restrict__ xq) {
  int i = blockIdx.x * 256 + threadIdx.x;
  if (i >= 256 * FCK) return;
  int s = i / FCK, k = i % FCK;
  float v = 0.f;
  if (k < H_)          v = selH[(size_t)s * HP + k];
  else if (k < 2 * H_) v = selH[(size_t)(256 + s) * HP + (k - H_)];
  float lr = v < 0.f ? 0.3f * v : v;
  float q = 0.f;
  if (k < 2 * H_) q = (lr - mu1[k]) * rsqrtf(var1[k] + 1e-3f) * g1[k] + be1[k];
  xq[i] = (f16)q;
}

__global__ void k_w1t(const float* __restrict__ W1, f16* __restrict__ W1T) {
  int i = blockIdx.x * 256 + threadIdx.x;
  if (i >= FCN * FCK) return;
  int cidx = i / FCK, k = i % FCK;
  W1T[i] = (f16)((cidx < 380 && k < 2 * H_) ? W1[(size_t)k * 380 + cidx] : 0.f);
}

__global__ __launch_bounds__(64)
void k_fc1(const f16* __restrict__ xq, const f16* __restrict__ W1T,
           const float* __restrict__ b1, float* __restrict__ z1) {
  __shared__ __align__(16) f16 ha[4][64 * 32];
  __shared__ __align__(16) f16 wb[4][64 * 32];
  const int lane = threadIdx.x;
  const int r0 = blockIdx.y * 64, c0 = blockIdx.x * 64;
  auto stage = [&](int buf, int kb) {
    #pragma unroll
    for (int i = 0; i < 4; i++) {
      int ch = lane + 64 * i;
      gl16(xq  + (size_t)(r0 + (ch >> 2)) * FCK + kb + (ch & 3) * 8, &ha[buf][i * 512]);
      gl16(W1T + (size_t)(c0 + (ch >> 2)) * FCK + kb + (ch & 3) * 8, &wb[buf][i * 512]);
    }
  };
  stage(0, 0); stage(1, 32); stage(2, 64);
  f32x4 acc[4][4];
  #pragma unroll
  for (int a = 0; a < 4; a++)
    #pragma unroll
    for (int b = 0; b < 4; b++) { f32x4 z = {0.f, 0.f, 0.f, 0.f}; acc[a][b] = z; }
  auto compute = [&](int buf) {
    half8 af[4], bf[4];
    #pragma unroll
    for (int rb = 0; rb < 4; rb++)
      af[rb] = *(const half8*)&ha[buf][(rb * 16 + (lane & 15)) * 32 + (lane >> 4) * 8];
    #pragma unroll
    for (int cb = 0; cb < 4; cb++)
      bf[cb] = *(const half8*)&wb[buf][(cb * 16 + (lane & 15)) * 32 + (lane >> 4) * 8];
    #pragma unroll
    for (int rb = 0; rb < 4; rb++)
      #pragma unroll
      for (int cb = 0; cb < 4; cb++)
        acc[rb][cb] = __builtin_amdgcn_mfma_f32_16x16x32_f16(af[rb], bf[cb], acc[rb][cb], 0, 0, 0);
  };
  for (int kb = 0; kb <= 116; ++kb) {
    stage((kb + 3) & 3, (kb + 3) * 32);
    WAITVM(24);
    compute(kb & 3);
  }
  WAITVM(16); compute(117 & 3);
  WAITVM(8);  compute(118 & 3);
  WAITVM(0);  compute(119 & 3);
  const int q4 = lane >> 4, c16 = lane & 15;
  #pragma unroll
  for (int rb = 0; rb < 4; rb++)
    #pragma unroll
    for (int cb = 0; cb < 4; cb++)
      #pragma unroll
      for (int q = 0; q < 4; q++) {
        int rl = rb * 16 + q4 * 4 + q;
        int col = c0 + cb * 16 + c16;
        float bias = (col < 380) ? b1[col] : 0.f;
        z1[(size_t)(r0 + rl) * FCN + col] = acc[rb][cb][q] + bias;
      }
}

__global__ void k_fc2(const float* __restrict__ z1, const float* __restrict__ g2,
                      const float* __restrict__ be2, const float* __restrict__ mu2,
                      const float* __restrict__ var2, const float* __restrict__ W2,
                      const float* __restrict__ b2, float* __restrict__ out) {
  int s = threadIdx.x;
  float a = 0.f;
  for (int jj = 0; jj < 380; jj++) {
    float v = z1[(size_t)s * FCN + jj];
    float lr = v < 0.f ? 0.3f * v : v;
    float q = (lr - mu2[jj]) * rsqrtf(var2[jj] + 1e-3f) * g2[jj] + be2[jj];
    a += q * W2[jj];
  }
  out[s] = a + b2[0];
}

// ---------------- host ----------------

extern "C" void kernel_launch(void* const* d_in, const int* in_sizes, int n_in,
                              void* d_out, int out_size, void* d_ws, size_t ws_size,
                              hipStream_t stream) {
  const int*   epix  = (const int*)d_in[0];
  const int*   lx    = (const int*)d_in[1];
  const int*   rx    = (const int*)d_in[2];
  const int*   totx  = (const int*)d_in[3];
  const float* embed = (const float*)d_in[4];
  const float* wx    = (const float*)d_in[5];
  const float* wh    = (const float*)d_in[6];
  const float* wmx   = (const float*)d_in[7];
  const float* wmh   = (const float*)d_in[8];
  const float* bb    = (const float*)d_in[9];
  const float* gx    = (const float*)d_in[10];
  const float* gh    = (const float*)d_in[11];
  const float* gmx   = (const float*)d_in[12];
  const float* gmh   = (const float*)d_in[13];
  const float* bn1g  = (const float*)d_in[14];
  const float* bn1b  = (const float*)d_in[15];
  const float* bn1m  = (const float*)d_in[16];
  const float* bn1v  = (const float*)d_in[17];
  const float* W1    = (const float*)d_in[18];
  const float* b1    = (const float*)d_in[19];
  const float* bn2g  = (const float*)d_in[20];
  const float* bn2b  = (const float*)d_in[21];
  const float* bn2m  = (const float*)d_in[22];
  const float* bn2v  = (const float*)d_in[23];
  const float* W2    = (const float*)d_in[24];
  const float* b2v   = (const float*)d_in[25];

  char* base = (char*)d_ws;
  size_t off = 0;
  auto alloc = [&](size_t n) { char* p = base + off; off = (off + n + 255) & ~(size_t)255; return p; };

  f16*   WmhT   = (f16*)  alloc((size_t)HP * HP * 2);
  f16*   WhT    = (f16*)  alloc((size_t)4 * HP * KB * 2);
  f16*   wmxT   = (f16*)  alloc((size_t)HP * 32 * 2);
  f16*   xe16   = (f16*)  alloc((size_t)TT * NR * 32 * 2);
  f16*   h0     = (f16*)  alloc((size_t)NR * HP * 2);
  f16*   h1     = (f16*)  alloc((size_t)NR * HP * 2);
  f16*   mbuf   = (f16*)  alloc((size_t)NR * KB * 2);
  float* cst    = (float*)alloc((size_t)NR * HP * 4);
  float* selH   = (float*)alloc((size_t)NR * HP * 4);
  int*   sel    = (int*)  alloc((size_t)NR * 4);
  float* inv_wh = (float*)alloc(7600 * 4);
  float* inv_wx = (float*)alloc(7600 * 4);
  float* inv_wmh= (float*)alloc(1900 * 4);
  float* inv_wmx= (float*)alloc(1900 * 4);
  f16*   xq     = (f16*)  alloc((size_t)256 * FCK * 2);
  f16*   W1T    = (f16*)  alloc((size_t)FCN * FCK * 2);
  float* z1     = (float*)alloc((size_t)256 * FCN * 4);
  (void)in_sizes; (void)n_in; (void)out_size; (void)ws_size;

  hipLaunchKernelGGL(k_norms, dim3(75), dim3(256), 0, stream,
                     wh, wx, wmh, wmx, gh, gx, gmh, gmx, inv_wh, inv_wx, inv_wmh, inv_wmx);
  hipLaunchKernelGGL(k_wmhT, dim3(60, 60), dim3(32, 8), 0, stream, wmh, inv_wmh, WmhT);
  hipLaunchKernelGGL(k_whT, dim3(60, 61, 4), dim3(32, 8), 0, stream,
                     wh, wx, bb, inv_wh, inv_wx, WhT);
  hipLaunchKernelGGL(k_wmxT, dim3((HP * 32 + 255) / 256), dim3(256), 0, stream,
                     wmx, inv_wmx, wmxT);
  hipLaunchKernelGGL(k_lens, dim3(1), dim3(256), 0, stream, epix, lx, rx, sel);
  hipLaunchKernelGGL(k_init, dim3((NR * HP + 255) / 256), dim3(256), 0, stream, h0, h1, cst);
  hipLaunchKernelGGL(k_xe16, dim3((TT * NR + 255) / 256), dim3(256), 0, stream,
                     totx, epix, embed, xe16);

  for (int t = 0; t < TT; t++) {
    const f16* hin = (t & 1) ? h1 : h0;
    f16*       ho  = (t & 1) ? h0 : h1;
    // stepA: nrow = Mt/16 -> per-group = 8*nrow; lnper = log2(8*nrow)
    int lnA = (t < TE) ? 8 : 7;                  // 1024 / 512 blocks
    int nblkA = 4 << lnA;
    hipLaunchKernelGGL(k_stepA, dim3(nblkA), dim3(64), 0, stream,
                       hin, WmhT, xe16 + (size_t)t * NR * 32, wmxT, mbuf, lnA);
    // stepB: nrow = Mt/64; lnper = log2(8*nrow)
    int lnB = (t < TE) ? 6 : 5;                  // 960 / 480 blocks
    int nblkB = 15 << lnB;
    hipLaunchKernelGGL(k_stepB, dim3(nblkB), dim3(64), 0, stream,
                       mbuf, WhT, cst, ho, selH, sel, t, lnB);
  }

  hipLaunchKernelGGL(k_xq, dim3((256 * FCK + 255) / 256), dim3(256), 0, stream,
                     selH, bn1g, bn1b, bn1m, bn1v, xq);
  hipLaunchKernelGGL(k_w1t, dim3((FCN * FCK + 255) / 256), dim3(256), 0, stream, W1, W1T);
  hipLaunchKernelGGL(k_fc1, dim3(6, 4), dim3(64), 0, stream, xq, W1T, b1, z1);
  hipLaunchKernelGGL(k_fc2, dim3(1), dim3(256), 0, stream,
                     z1, bn2g, bn2b, bn2m, bn2v, W2, b2v, (float*)d_out);
}